// Round 2
// baseline (202.478 us; speedup 1.0000x reference)
//
#include <hip/hip_runtime.h>

// ---------------------------------------------------------------------------
// 12-qubit real statevector QNN, fully register-resident.
//
// Wire w (0..11) -> bit of stored index y:  w<6 -> lane bit w ; w>=6 -> reg bit w-6.
// stored(y) = psi(A y), A = G^{-t} after t CNOT-ladders, G: y'_k = y_k ^ y_{k-1}.
// RY(w) at layer t: pair mask  m = G^t e_w  (bits {w+d : C(t,d) odd}),
//                   side mask  s = row_w(G^{16-t}) (bits {w-d : C(16-t,d) odd}).
// <Z_w> sign mask after 4 layers: row_w(G^12) = bits {w, w-4, w-8}.
// ---------------------------------------------------------------------------

constexpr unsigned pair_mask(int t, int w) {
    unsigned m = 0;
    for (int d = 0; w + d < 12; ++d)
        if ((d & ~(unsigned)t) == 0) m |= 1u << (w + d);
    return m;
}
constexpr unsigned side_mask(int t, int w) {
    unsigned s = 16u - (unsigned)t;
    unsigned m = 0;
    for (int d = 0; d <= w; ++d)
        if (((unsigned)d & ~s) == 0) m |= 1u << (w - d);
    return m;
}
constexpr unsigned z_mask(int w) {
    unsigned m = 0;
    for (int u = w; u >= 0; u -= 4) m |= 1u << u;
    return m;
}

static_assert(pair_mask(1, 0) == 0b11u, "");
static_assert(pair_mask(2, 3) == ((1u << 3) | (1u << 5)), "");
static_assert(pair_mask(4, 7) == ((1u << 7) | (1u << 11)), "");
static_assert(side_mask(1, 2) == 0b111u, "");
static_assert(side_mask(4, 11) == ((1u << 11) | (1u << 7) | (1u << 3)), "");
static_assert(z_mask(9) == ((1u << 9) | (1u << 5) | (1u << 1)), "");

// One RY butterfly over the 64-register state.
// LM/RM: lane/register parts of the pairing XOR mask. SL/SR: side-parity masks.
// Element (lane l, reg r): side = par(SL&l) ^ par(SR&r);
// new = c*old + (side ? +s : -s) * partner.
template <unsigned LM, unsigned RM, unsigned SL, unsigned SR>
__device__ __forceinline__ void ry(float (&v)[64], float c, float s, unsigned lane) {
    const float ss = (__popc(SL & lane) & 1) ? s : -s;  // sign for par(SR&r)==0
    if constexpr (RM == 0u) {
#pragma unroll
        for (int r = 0; r < 64; ++r) {
            float p = __shfl_xor(v[r], (int)LM, 64);
            float t = p * ss;
            v[r] = (__builtin_popcount(SR & (unsigned)r) & 1) ? fmaf(c, v[r], -t)
                                                              : fmaf(c, v[r], t);
        }
    } else {
#pragma unroll
        for (int r = 0; r < 64; ++r) {
            const int r2 = r ^ (int)RM;
            if (r > r2) continue;  // each pair once (compile-time after unroll)
            float a = v[r], b = v[r2];
            float pa = (LM != 0u) ? __shfl_xor(b, (int)LM, 64) : b;
            float pb = (LM != 0u) ? __shfl_xor(a, (int)LM, 64) : a;
            float ta = pa * ss, tb = pb * ss;
            v[r]  = (__builtin_popcount(SR & (unsigned)r)  & 1) ? fmaf(c, a, -ta)
                                                                : fmaf(c, a, ta);
            v[r2] = (__builtin_popcount(SR & (unsigned)r2) & 1) ? fmaf(c, b, -tb)
                                                                : fmaf(c, b, tb);
        }
    }
}

#define RY_APPLY(T, W)                                                              \
    ry<(pair_mask(T, W) & 63u), (pair_mask(T, W) >> 6), (side_mask(T, W) & 63u),    \
       (side_mask(T, W) >> 6)>(v, cpar[W], spar[W], lane);

#define LAYER(T)                                                      \
    RY_APPLY(T, 0) RY_APPLY(T, 1) RY_APPLY(T, 2) RY_APPLY(T, 3)       \
    RY_APPLY(T, 4) RY_APPLY(T, 5) RY_APPLY(T, 6) RY_APPLY(T, 7)       \
    RY_APPLY(T, 8) RY_APPLY(T, 9) RY_APPLY(T, 10) RY_APPLY(T, 11)

__global__ void __launch_bounds__(256) qnn12_kernel(
    const float* __restrict__ state, const float* __restrict__ params,
    const float* __restrict__ head_w, const float* __restrict__ head_b,
    float* __restrict__ out, int B) {
    __shared__ float Wt[4096];

    const int tid = threadIdx.x;
    const unsigned lane = (unsigned)(tid & 63);
    const int wid = tid >> 6;
    const int sample = blockIdx.x * 4 + wid;
    const bool active = sample < B;

    // ---- per-block Z-weight table: W[y] = sum_w hw[w]*(1-2*par(z_mask(w)&y))
    {
        float hwv[12];
#pragma unroll
        for (int w = 0; w < 12; ++w) hwv[w] = head_w[w];
#pragma unroll
        for (int k = 0; k < 16; ++k) {
            int i = tid + (k << 8);
            float a = 0.f;
#pragma unroll
            for (int w = 0; w < 12; ++w)
                a += (__builtin_popcount(z_mask(w) & (unsigned)i) & 1) ? -hwv[w] : hwv[w];
            Wt[i] = a;
        }
    }
    __syncthreads();

    // ---- angles: lanes 0..11 hold encoding angles, lanes 16..27 hold params
    float ang = 0.f;
    if (active && lane < 12u) ang = state[sample * 12 + (int)lane];
    else if (lane >= 16u && lane < 28u) ang = params[lane - 16u];
    float sv_, cv_;
    __sincosf(0.5f * ang, &sv_, &cv_);

    float cpar[12], spar[12];
#pragma unroll
    for (int w = 0; w < 12; ++w) {
        cpar[w] = __shfl(cv_, 16 + w, 64);
        spar[w] = __shfl(sv_, 16 + w, 64);
    }

    // ---- encoding: product state. lane-bit prefactor, then reg-bit tree.
    float pre = 1.f;
#pragma unroll
    for (int w = 0; w < 6; ++w) {
        float cw = __shfl(cv_, w, 64), sw = __shfl(sv_, w, 64);
        pre *= ((lane >> w) & 1u) ? sw : cw;
    }
    float fc[6], fs[6];
#pragma unroll
    for (int i = 0; i < 6; ++i) {
        fc[i] = __shfl(cv_, 6 + i, 64);
        fs[i] = __shfl(sv_, 6 + i, 64);
    }

    float v[64];
    {
        float t4[16];
#pragma unroll
        for (int j = 0; j < 16; ++j) {
            float x = pre;
            x *= (j & 1) ? fs[0] : fc[0];
            x *= (j & 2) ? fs[1] : fc[1];
            x *= (j & 4) ? fs[2] : fc[2];
            x *= (j & 8) ? fs[3] : fc[3];
            t4[j] = x;
        }
#pragma unroll
        for (int r = 0; r < 64; ++r) {
            float x = t4[r & 15];
            x *= ((r >> 4) & 1) ? fs[4] : fc[4];
            x *= ((r >> 5) & 1) ? fs[5] : fc[5];
            v[r] = x;
        }
    }

    // ---- 4 variational layers (CNOT ladders folded into masks)
    LAYER(1)
    LAYER(2)
    LAYER(3)
    LAYER(4)

    // ---- epilogue: out = sum_y v(y)^2 * W[y] + b   (y = (r<<6)|lane)
    float a0 = 0.f, a1 = 0.f, a2 = 0.f, a3 = 0.f;
#pragma unroll
    for (int r = 0; r < 64; r += 4) {
        float w0 = Wt[((r + 0) << 6) + (int)lane];
        float w1 = Wt[((r + 1) << 6) + (int)lane];
        float w2 = Wt[((r + 2) << 6) + (int)lane];
        float w3 = Wt[((r + 3) << 6) + (int)lane];
        a0 = fmaf(v[r + 0] * w0, v[r + 0], a0);
        a1 = fmaf(v[r + 1] * w1, v[r + 1], a1);
        a2 = fmaf(v[r + 2] * w2, v[r + 2], a2);
        a3 = fmaf(v[r + 3] * w3, v[r + 3], a3);
    }
    float acc = (a0 + a1) + (a2 + a3);
#pragma unroll
    for (int off = 32; off > 0; off >>= 1) acc += __shfl_xor(acc, off, 64);

    if (active && lane == 0u) out[sample] = acc + head_b[0];
}

extern "C" void kernel_launch(void* const* d_in, const int* in_sizes, int n_in,
                              void* d_out, int out_size, void* d_ws, size_t ws_size,
                              hipStream_t stream) {
    const float* state  = (const float*)d_in[0];
    const float* params = (const float*)d_in[1];
    const float* head_w = (const float*)d_in[2];
    const float* head_b = (const float*)d_in[3];
    float* out = (float*)d_out;

    const int B = in_sizes[0] / 12;          // 8192
    const int blocks = (B + 3) / 4;          // 4 waves/block, 1 sample/wave
    hipLaunchKernelGGL(qnn12_kernel, dim3(blocks), dim3(256), 0, stream,
                       state, params, head_w, head_b, out, B);
}

// Round 3
// 201.906 us; speedup vs baseline: 1.0028x; 1.0028x over previous
//
#include <hip/hip_runtime.h>

// ---------------------------------------------------------------------------
// 12-qubit real statevector QNN, fully register-resident.
//
// Wire w (0..11) -> bit of stored index y:  w<6 -> lane bit w ; w>=6 -> reg bit w-6.
// stored(y) = psi(A y), A = G^{-t} after t CNOT-ladders, G: y'_k = y_k ^ y_{k-1}.
// RY(w) at layer t: pair mask  m = G^t e_w  (bits {w+d : C(t,d) odd}),
//                   side mask  s = row_w(G^{16-t}) (bits {w-d : C(16-t,d) odd}).
// <Z_w> sign mask after 4 layers: row_w(G^12) = bits {w, w-4, w-8}.
//
// R2 lesson: default arch-VGPR cap pushed v[64] into AGPRs (VGPR_Count=52),
// paying accvgpr round-trips around every ds_bpermute. launch_bounds(256,2)
// raises the cap; c/s broadcast per-gate via readlane (SGPR) instead of
// persistent cpar/spar arrays (-24 VGPR pressure).
// ---------------------------------------------------------------------------

constexpr unsigned pair_mask(int t, int w) {
    unsigned m = 0;
    for (int d = 0; w + d < 12; ++d)
        if ((d & ~(unsigned)t) == 0) m |= 1u << (w + d);
    return m;
}
constexpr unsigned side_mask(int t, int w) {
    unsigned s = 16u - (unsigned)t;
    unsigned m = 0;
    for (int d = 0; d <= w; ++d)
        if (((unsigned)d & ~s) == 0) m |= 1u << (w - d);
    return m;
}
constexpr unsigned z_mask(int w) {
    unsigned m = 0;
    for (int u = w; u >= 0; u -= 4) m |= 1u << u;
    return m;
}

static_assert(pair_mask(1, 0) == 0b11u, "");
static_assert(pair_mask(2, 3) == ((1u << 3) | (1u << 5)), "");
static_assert(pair_mask(4, 7) == ((1u << 7) | (1u << 11)), "");
static_assert(side_mask(1, 2) == 0b111u, "");
static_assert(side_mask(4, 11) == ((1u << 11) | (1u << 7) | (1u << 3)), "");
static_assert(z_mask(9) == ((1u << 9) | (1u << 5) | (1u << 1)), "");

// One RY butterfly over the 64-register state.
// LM/RM: lane/register parts of the pairing XOR mask. SL/SR: side-parity masks.
// Element (lane l, reg r): side = par(SL&l) ^ par(SR&r);
// new = c*old + (side ? +s : -s) * partner.
template <unsigned LM, unsigned RM, unsigned SL, unsigned SR>
__device__ __forceinline__ void ry(float (&v)[64], float c, float s, unsigned lane) {
    const float ss = (__popc(SL & lane) & 1) ? s : -s;  // sign for par(SR&r)==0
    if constexpr (RM == 0u) {
#pragma unroll
        for (int r = 0; r < 64; ++r) {
            float p = __shfl_xor(v[r], (int)LM, 64);
            float t = p * ss;
            v[r] = (__builtin_popcount(SR & (unsigned)r) & 1) ? fmaf(c, v[r], -t)
                                                              : fmaf(c, v[r], t);
        }
    } else {
#pragma unroll
        for (int r = 0; r < 64; ++r) {
            const int r2 = r ^ (int)RM;
            if (r > r2) continue;  // each pair once (compile-time after unroll)
            float a = v[r], b = v[r2];
            float pa = (LM != 0u) ? __shfl_xor(b, (int)LM, 64) : b;
            float pb = (LM != 0u) ? __shfl_xor(a, (int)LM, 64) : a;
            float ta = pa * ss, tb = pb * ss;
            v[r]  = (__builtin_popcount(SR & (unsigned)r)  & 1) ? fmaf(c, a, -ta)
                                                                : fmaf(c, a, ta);
            v[r2] = (__builtin_popcount(SR & (unsigned)r2) & 1) ? fmaf(c, b, -tb)
                                                                : fmaf(c, b, tb);
        }
    }
}

// c,s broadcast from lane 16+W each gate -> v_readlane/SGPR, no VGPR arrays.
#define RY_APPLY(T, W)                                                               \
    {                                                                                \
        const float c_ = __shfl(cv_, 16 + (W), 64);                                  \
        const float s_ = __shfl(sv_, 16 + (W), 64);                                  \
        ry<(pair_mask(T, W) & 63u), (pair_mask(T, W) >> 6), (side_mask(T, W) & 63u), \
           (side_mask(T, W) >> 6)>(v, c_, s_, lane);                                 \
    }

#define LAYER(T)                                                      \
    RY_APPLY(T, 0) RY_APPLY(T, 1) RY_APPLY(T, 2) RY_APPLY(T, 3)       \
    RY_APPLY(T, 4) RY_APPLY(T, 5) RY_APPLY(T, 6) RY_APPLY(T, 7)       \
    RY_APPLY(T, 8) RY_APPLY(T, 9) RY_APPLY(T, 10) RY_APPLY(T, 11)

__global__ void __launch_bounds__(256, 2) qnn12_kernel(
    const float* __restrict__ state, const float* __restrict__ params,
    const float* __restrict__ head_w, const float* __restrict__ head_b,
    float* __restrict__ out, int B) {
    __shared__ float Wt[4096];

    const int tid = threadIdx.x;
    const unsigned lane = (unsigned)(tid & 63);
    const int wid = tid >> 6;
    const int sample = blockIdx.x * 4 + wid;
    const bool active = sample < B;

    // ---- per-block Z-weight table: W[y] = sum_w hw[w]*(1-2*par(z_mask(w)&y))
    {
        float hwv[12];
#pragma unroll
        for (int w = 0; w < 12; ++w) hwv[w] = head_w[w];
#pragma unroll
        for (int k = 0; k < 16; ++k) {
            int i = tid + (k << 8);
            float a = 0.f;
#pragma unroll
            for (int w = 0; w < 12; ++w)
                a += (__builtin_popcount(z_mask(w) & (unsigned)i) & 1) ? -hwv[w] : hwv[w];
            Wt[i] = a;
        }
    }
    __syncthreads();

    // ---- angles: lanes 0..11 hold encoding angles, lanes 16..27 hold params
    float ang = 0.f;
    if (active && lane < 12u) ang = state[sample * 12 + (int)lane];
    else if (lane >= 16u && lane < 28u) ang = params[lane - 16u];
    float sv_, cv_;
    __sincosf(0.5f * ang, &sv_, &cv_);

    // ---- encoding: product state. lane-bit prefactor, then reg-bit tree.
    float pre = 1.f;
#pragma unroll
    for (int w = 0; w < 6; ++w) {
        float cw = __shfl(cv_, w, 64), sw = __shfl(sv_, w, 64);
        pre *= ((lane >> w) & 1u) ? sw : cw;
    }
    float fc[6], fs[6];
#pragma unroll
    for (int i = 0; i < 6; ++i) {
        fc[i] = __shfl(cv_, 6 + i, 64);
        fs[i] = __shfl(sv_, 6 + i, 64);
    }

    float v[64];
    {
        float t4[16];
#pragma unroll
        for (int j = 0; j < 16; ++j) {
            float x = pre;
            x *= (j & 1) ? fs[0] : fc[0];
            x *= (j & 2) ? fs[1] : fc[1];
            x *= (j & 4) ? fs[2] : fc[2];
            x *= (j & 8) ? fs[3] : fc[3];
            t4[j] = x;
        }
#pragma unroll
        for (int r = 0; r < 64; ++r) {
            float x = t4[r & 15];
            x *= ((r >> 4) & 1) ? fs[4] : fc[4];
            x *= ((r >> 5) & 1) ? fs[5] : fc[5];
            v[r] = x;
        }
    }

    // ---- 4 variational layers (CNOT ladders folded into masks)
    LAYER(1)
    LAYER(2)
    LAYER(3)
    LAYER(4)

    // ---- epilogue: out = sum_y v(y)^2 * W[y] + b   (y = (r<<6)|lane)
    float a0 = 0.f, a1 = 0.f, a2 = 0.f, a3 = 0.f;
#pragma unroll
    for (int r = 0; r < 64; r += 4) {
        float w0 = Wt[((r + 0) << 6) + (int)lane];
        float w1 = Wt[((r + 1) << 6) + (int)lane];
        float w2 = Wt[((r + 2) << 6) + (int)lane];
        float w3 = Wt[((r + 3) << 6) + (int)lane];
        a0 = fmaf(v[r + 0] * w0, v[r + 0], a0);
        a1 = fmaf(v[r + 1] * w1, v[r + 1], a1);
        a2 = fmaf(v[r + 2] * w2, v[r + 2], a2);
        a3 = fmaf(v[r + 3] * w3, v[r + 3], a3);
    }
    float acc = (a0 + a1) + (a2 + a3);
#pragma unroll
    for (int off = 32; off > 0; off >>= 1) acc += __shfl_xor(acc, off, 64);

    if (active && lane == 0u) out[sample] = acc + head_b[0];
}

extern "C" void kernel_launch(void* const* d_in, const int* in_sizes, int n_in,
                              void* d_out, int out_size, void* d_ws, size_t ws_size,
                              hipStream_t stream) {
    const float* state  = (const float*)d_in[0];
    const float* params = (const float*)d_in[1];
    const float* head_w = (const float*)d_in[2];
    const float* head_b = (const float*)d_in[3];
    float* out = (float*)d_out;

    const int B = in_sizes[0] / 12;          // 8192
    const int blocks = (B + 3) / 4;          // 4 waves/block, 1 sample/wave
    hipLaunchKernelGGL(qnn12_kernel, dim3(blocks), dim3(256), 0, stream,
                       state, params, head_w, head_b, out, B);
}

// Round 4
// 200.020 us; speedup vs baseline: 1.0123x; 1.0094x over previous
//
#include <hip/hip_runtime.h>

// ---------------------------------------------------------------------------
// 12-qubit real statevector QNN, fully register-resident.
//
// Wire w (0..11) -> bit of stored index y:  w<6 -> lane bit w ; w>=6 -> reg bit w-6.
// stored(y) = psi(A y), A = G^{-t} after t CNOT-ladders, G: y'_k = y_k ^ y_{k-1}.
// RY(w) at layer t: pair mask  m = G^t e_w  (bits {w+d : C(t,d) odd}),
//                   side mask  s = row_w(G^{16-t}) (bits {w-d : C(16-t,d) odd}).
// <Z_w> sign mask after 4 layers: row_w(G^12) = bits {w, w-4, w-8}.
//
// R2/R3 lesson: allocator homes v[64] in AGPRs (VGPR_Count=52) and pays
// v_accvgpr round-trips at every ds_bpermute (~44us extra VALU, measured).
// launch_bounds(256,2) did NOT change the split. This round: pin every def
// of v[r] to an arch VGPR via empty asm "+v" constraints (zero runtime ops).
// ---------------------------------------------------------------------------

constexpr unsigned pair_mask(int t, int w) {
    unsigned m = 0;
    for (int d = 0; w + d < 12; ++d)
        if ((d & ~(unsigned)t) == 0) m |= 1u << (w + d);
    return m;
}
constexpr unsigned side_mask(int t, int w) {
    unsigned s = 16u - (unsigned)t;
    unsigned m = 0;
    for (int d = 0; d <= w; ++d)
        if (((unsigned)d & ~s) == 0) m |= 1u << (w - d);
    return m;
}
constexpr unsigned z_mask(int w) {
    unsigned m = 0;
    for (int u = w; u >= 0; u -= 4) m |= 1u << u;
    return m;
}

static_assert(pair_mask(1, 0) == 0b11u, "");
static_assert(pair_mask(2, 3) == ((1u << 3) | (1u << 5)), "");
static_assert(pair_mask(4, 7) == ((1u << 7) | (1u << 11)), "");
static_assert(side_mask(1, 2) == 0b111u, "");
static_assert(side_mask(4, 11) == ((1u << 11) | (1u << 7) | (1u << 3)), "");
static_assert(z_mask(9) == ((1u << 9) | (1u << 5) | (1u << 1)), "");

// Pin a float's current value to an arch VGPR (not AGPR) at this point.
// Empty asm, zero instructions; constrains only register class.
__device__ __forceinline__ void pin_v(float& x) { asm("" : "+v"(x)); }

// One RY butterfly over the 64-register state.
// LM/RM: lane/register parts of the pairing XOR mask. SL/SR: side-parity masks.
// Element (lane l, reg r): side = par(SL&l) ^ par(SR&r);
// new = c*old + (side ? +s : -s) * partner.
template <unsigned LM, unsigned RM, unsigned SL, unsigned SR>
__device__ __forceinline__ void ry(float (&v)[64], float c, float s, unsigned lane) {
    const float ss = (__popc(SL & lane) & 1) ? s : -s;  // sign for par(SR&r)==0
    if constexpr (RM == 0u) {
#pragma unroll
        for (int r = 0; r < 64; ++r) {
            float p = __shfl_xor(v[r], (int)LM, 64);
            float t = p * ss;
            float nv = (__builtin_popcount(SR & (unsigned)r) & 1) ? fmaf(c, v[r], -t)
                                                                  : fmaf(c, v[r], t);
            pin_v(nv);
            v[r] = nv;
        }
    } else {
#pragma unroll
        for (int r = 0; r < 64; ++r) {
            const int r2 = r ^ (int)RM;
            if (r > r2) continue;  // each pair once (compile-time after unroll)
            float a = v[r], b = v[r2];
            float pa = (LM != 0u) ? __shfl_xor(b, (int)LM, 64) : b;
            float pb = (LM != 0u) ? __shfl_xor(a, (int)LM, 64) : a;
            float ta = pa * ss, tb = pb * ss;
            float na = (__builtin_popcount(SR & (unsigned)r)  & 1) ? fmaf(c, a, -ta)
                                                                   : fmaf(c, a, ta);
            float nb = (__builtin_popcount(SR & (unsigned)r2) & 1) ? fmaf(c, b, -tb)
                                                                   : fmaf(c, b, tb);
            pin_v(na);
            pin_v(nb);
            v[r] = na;
            v[r2] = nb;
        }
    }
}

// c,s broadcast from lane 16+W each gate -> v_readlane/SGPR, no VGPR arrays.
#define RY_APPLY(T, W)                                                               \
    {                                                                                \
        const float c_ = __shfl(cv_, 16 + (W), 64);                                  \
        const float s_ = __shfl(sv_, 16 + (W), 64);                                  \
        ry<(pair_mask(T, W) & 63u), (pair_mask(T, W) >> 6), (side_mask(T, W) & 63u), \
           (side_mask(T, W) >> 6)>(v, c_, s_, lane);                                 \
    }

#define LAYER(T)                                                      \
    RY_APPLY(T, 0) RY_APPLY(T, 1) RY_APPLY(T, 2) RY_APPLY(T, 3)       \
    RY_APPLY(T, 4) RY_APPLY(T, 5) RY_APPLY(T, 6) RY_APPLY(T, 7)       \
    RY_APPLY(T, 8) RY_APPLY(T, 9) RY_APPLY(T, 10) RY_APPLY(T, 11)

__global__ void __launch_bounds__(256, 2) qnn12_kernel(
    const float* __restrict__ state, const float* __restrict__ params,
    const float* __restrict__ head_w, const float* __restrict__ head_b,
    float* __restrict__ out, int B) {
    __shared__ float Wt[4096];

    const int tid = threadIdx.x;
    const unsigned lane = (unsigned)(tid & 63);
    const int wid = tid >> 6;
    const int sample = blockIdx.x * 4 + wid;
    const bool active = sample < B;

    // ---- per-block Z-weight table: W[y] = sum_w hw[w]*(1-2*par(z_mask(w)&y))
    {
        float hwv[12];
#pragma unroll
        for (int w = 0; w < 12; ++w) hwv[w] = head_w[w];
#pragma unroll
        for (int k = 0; k < 16; ++k) {
            int i = tid + (k << 8);
            float a = 0.f;
#pragma unroll
            for (int w = 0; w < 12; ++w)
                a += (__builtin_popcount(z_mask(w) & (unsigned)i) & 1) ? -hwv[w] : hwv[w];
            Wt[i] = a;
        }
    }
    __syncthreads();

    // ---- angles: lanes 0..11 hold encoding angles, lanes 16..27 hold params
    float ang = 0.f;
    if (active && lane < 12u) ang = state[sample * 12 + (int)lane];
    else if (lane >= 16u && lane < 28u) ang = params[lane - 16u];
    float sv_, cv_;
    __sincosf(0.5f * ang, &sv_, &cv_);

    // ---- encoding: product state. lane-bit prefactor, then reg-bit tree.
    float pre = 1.f;
#pragma unroll
    for (int w = 0; w < 6; ++w) {
        float cw = __shfl(cv_, w, 64), sw = __shfl(sv_, w, 64);
        pre *= ((lane >> w) & 1u) ? sw : cw;
    }
    float fc[6], fs[6];
#pragma unroll
    for (int i = 0; i < 6; ++i) {
        fc[i] = __shfl(cv_, 6 + i, 64);
        fs[i] = __shfl(sv_, 6 + i, 64);
    }

    float v[64];
    {
        float t4[16];
#pragma unroll
        for (int j = 0; j < 16; ++j) {
            float x = pre;
            x *= (j & 1) ? fs[0] : fc[0];
            x *= (j & 2) ? fs[1] : fc[1];
            x *= (j & 4) ? fs[2] : fc[2];
            x *= (j & 8) ? fs[3] : fc[3];
            t4[j] = x;
        }
#pragma unroll
        for (int r = 0; r < 64; ++r) {
            float x = t4[r & 15];
            x *= ((r >> 4) & 1) ? fs[4] : fc[4];
            x *= ((r >> 5) & 1) ? fs[5] : fc[5];
            pin_v(x);
            v[r] = x;
        }
    }

    // ---- 4 variational layers (CNOT ladders folded into masks)
    LAYER(1)
    LAYER(2)
    LAYER(3)
    LAYER(4)

    // ---- epilogue: out = sum_y v(y)^2 * W[y] + b   (y = (r<<6)|lane)
    float a0 = 0.f, a1 = 0.f, a2 = 0.f, a3 = 0.f;
#pragma unroll
    for (int r = 0; r < 64; r += 4) {
        float w0 = Wt[((r + 0) << 6) + (int)lane];
        float w1 = Wt[((r + 1) << 6) + (int)lane];
        float w2 = Wt[((r + 2) << 6) + (int)lane];
        float w3 = Wt[((r + 3) << 6) + (int)lane];
        a0 = fmaf(v[r + 0] * w0, v[r + 0], a0);
        a1 = fmaf(v[r + 1] * w1, v[r + 1], a1);
        a2 = fmaf(v[r + 2] * w2, v[r + 2], a2);
        a3 = fmaf(v[r + 3] * w3, v[r + 3], a3);
    }
    float acc = (a0 + a1) + (a2 + a3);
#pragma unroll
    for (int off = 32; off > 0; off >>= 1) acc += __shfl_xor(acc, off, 64);

    if (active && lane == 0u) out[sample] = acc + head_b[0];
}

extern "C" void kernel_launch(void* const* d_in, const int* in_sizes, int n_in,
                              void* d_out, int out_size, void* d_ws, size_t ws_size,
                              hipStream_t stream) {
    const float* state  = (const float*)d_in[0];
    const float* params = (const float*)d_in[1];
    const float* head_w = (const float*)d_in[2];
    const float* head_b = (const float*)d_in[3];
    float* out = (float*)d_out;

    const int B = in_sizes[0] / 12;          // 8192
    const int blocks = (B + 3) / 4;          // 4 waves/block, 1 sample/wave
    hipLaunchKernelGGL(qnn12_kernel, dim3(blocks), dim3(256), 0, stream,
                       state, params, head_w, head_b, out, B);
}